// Round 14
// baseline (270.608 us; speedup 1.0000x reference)
//
#include <hip/hip_runtime.h>
#include <stdint.h>
#include <string.h>

#define N_USER 50000
#define N_ITEM 50000
#define N_EDGE 600000
#define D 128
#define NTOT 150000      // 3 * 50000 destination slots (uu | ub | iu)
#define ETOT 1800000
#define NB 293           // buckets = ceil(NTOT / SPAN)
#define BSH 9
#define SPAN 512         // slots per bucket
#define CHUNK 4096       // edges per block in bucket kernels (16/thread)
#define CAP 7168         // fixed bucket capacity (expected max ~6450, 13-sigma margin)

typedef unsigned short u16;
typedef unsigned int   u32;
typedef __attribute__((ext_vector_type(8))) short short8;   // 8 bf16 (MFMA A/B frag)
typedef __attribute__((ext_vector_type(4))) float floatx4;  // MFMA C/D frag

static __device__ __forceinline__ u16 f2b(float f) {        // f32 -> bf16 RNE
  u32 x; memcpy(&x, &f, 4);
  u32 r = x + 0x7fffu + ((x >> 16) & 1u);
  return (u16)(r >> 16);
}
static __device__ __forceinline__ float blo2f(u32 v) {
  u32 x = v << 16; float f; memcpy(&f, &x, 4); return f;
}
static __device__ __forceinline__ float bhi2f(u32 v) {
  u32 x = v & 0xffff0000u; float f; memcpy(&f, &x, 4); return f;
}

// streaming f32->bf16 conversion: 8 float4-groups per thread from group cbase.
// Total 3.2M groups (fu then fi). Rides as filler blocks on under-utilized launches.
static __device__ __forceinline__ void conv_chunk(int cbase,
    const float* __restrict__ fu, const float* __restrict__ fi,
    u16* __restrict__ fb_u, u16* __restrict__ fb_i) {
#pragma unroll
  for (int u = 0; u < 8; ++u) {
    int gid = cbase + u * 256 + (int)threadIdx.x;
    if (gid < 3200000) {
      const float* src = fu; u16* dst = fb_u; int g = gid;
      if (g >= 1600000) { g -= 1600000; src = fi; dst = fb_i; }
      float4 v = ((const float4*)src)[g];
      union { u16 q[4]; uint2 d; } pk;
      pk.q[0] = f2b(v.x); pk.q[1] = f2b(v.y); pk.q[2] = f2b(v.z); pk.q[3] = f2b(v.w);
      ((uint2*)dst)[g] = pk.d;
    }
  }
}

// gather-mean body (proven v5): half-wave per slot, uint2/lane, shfl-broadcast
// edge srcs, 8/4/1 load batches. Writes bf16 mean into d_out per layout.
static __device__ __forceinline__ void mean_slot(int slot, int lane,
    const u16* __restrict__ fb, const int* __restrict__ off,
    const u16* __restrict__ ssrc, u16* __restrict__ ob) {
  int t = slot / N_USER;
  int d = slot - t * N_USER;
  int s = off[slot], e = off[slot + 1];
  int n = e - s;
  int my_src = (lane < n) ? (int)ssrc[s + lane] : 0;
  float a0 = 0.f, a1 = 0.f, a2 = 0.f, a3 = 0.f;
  int m = (n < 32) ? n : 32;
  int i = 0;
  for (; i + 8 <= m; i += 8) {
    int sA[8];
#pragma unroll
    for (int k = 0; k < 8; ++k) sA[k] = __shfl(my_src, i + k, 32);
    uint2 v[8];
#pragma unroll
    for (int k = 0; k < 8; ++k) v[k] = ((const uint2*)(fb + (size_t)sA[k] * D))[lane];
#pragma unroll
    for (int k = 0; k < 8; ++k) {
      a0 += blo2f(v[k].x); a1 += bhi2f(v[k].x);
      a2 += blo2f(v[k].y); a3 += bhi2f(v[k].y);
    }
  }
  for (; i + 4 <= m; i += 4) {
    int s0 = __shfl(my_src, i, 32);
    int s1 = __shfl(my_src, i + 1, 32);
    int s2 = __shfl(my_src, i + 2, 32);
    int s3 = __shfl(my_src, i + 3, 32);
    uint2 v0 = ((const uint2*)(fb + (size_t)s0 * D))[lane];
    uint2 v1 = ((const uint2*)(fb + (size_t)s1 * D))[lane];
    uint2 v2 = ((const uint2*)(fb + (size_t)s2 * D))[lane];
    uint2 v3 = ((const uint2*)(fb + (size_t)s3 * D))[lane];
    a0 += blo2f(v0.x) + blo2f(v1.x) + blo2f(v2.x) + blo2f(v3.x);
    a1 += bhi2f(v0.x) + bhi2f(v1.x) + bhi2f(v2.x) + bhi2f(v3.x);
    a2 += blo2f(v0.y) + blo2f(v1.y) + blo2f(v2.y) + blo2f(v3.y);
    a3 += bhi2f(v0.y) + bhi2f(v1.y) + bhi2f(v2.y) + bhi2f(v3.y);
  }
  for (; i < m; ++i) {
    int sr = __shfl(my_src, i, 32);
    uint2 v = ((const uint2*)(fb + (size_t)sr * D))[lane];
    a0 += blo2f(v.x); a1 += bhi2f(v.x);
    a2 += blo2f(v.y); a3 += bhi2f(v.y);
  }
  for (int j = s + 32; j < e; ++j) {
    int sr = ssrc[j];
    uint2 v = ((const uint2*)(fb + (size_t)sr * D))[lane];
    a0 += blo2f(v.x); a1 += bhi2f(v.x);
    a2 += blo2f(v.y); a3 += bhi2f(v.y);
  }
  float inv = (n > 0) ? 1.0f / (float)n : 0.f;
  u32 p0 = (u32)f2b(a0 * inv) | ((u32)f2b(a1 * inv) << 16);
  u32 p1 = (u32)f2b(a2 * inv) | ((u32)f2b(a3 * inv) << 16);
  u32* mrow;
  if (t == 0)      mrow = (u32*)(ob + (size_t)d * 256);              // mean_uu
  else if (t == 2) mrow = (u32*)(ob + (size_t)d * 256 + 128);        // mean_iu
  else             mrow = (u32*)(ob + 12800000 + (size_t)d * 256);   // mean_ub
  ((uint2*)mrow)[lane] = make_uint2(p0, p1);
}

// ---- bplace v2: fixed-capacity buckets, NO histogram pre-pass. [0,440) place;
//      [440,443) weight transpose; [443,1225) conversion part 1 ----
__global__ void __launch_bounds__(256) k_bplace(
    const int* __restrict__ suu, const int* __restrict__ duu,
    const int* __restrict__ sub, const int* __restrict__ dub,
    const int* __restrict__ siu, const int* __restrict__ diu,
    int* __restrict__ cursor, u32* __restrict__ ebuf,
    const float* __restrict__ W0, const float* __restrict__ W1,
    const float* __restrict__ W2, u16* __restrict__ WT,
    const float* __restrict__ fu, const float* __restrict__ fi,
    u16* __restrict__ fb_u, u16* __restrict__ fb_i) {
  int bid = blockIdx.x;
  if (bid >= 443) {                      // conversion filler part 1
    conv_chunk((bid - 443) * 2048, fu, fi, fb_u, fb_i);
    return;
  }
  if (bid >= 440) {                      // weight transpose + bf16 (stacked)
    int wsel = bid - 440;
    for (int idx = threadIdx.x; idx < D * D; idx += 256) {
      int n = idx >> 7, k = idx & 127;
      if (wsel == 0)      WT[n * 256 + k]       = f2b(W0[k * D + n]);
      else if (wsel == 1) WT[n * 256 + 128 + k] = f2b(W2[k * D + n]);
      else                WT[32768 + n * D + k] = f2b(W1[k * D + n]);
    }
    return;
  }
  __shared__ int h[NB];
  int t = threadIdx.x;
  for (int i = t; i < NB; i += 256) h[i] = 0;
  __syncthreads();
  int base = bid * CHUNK;
  u32 pay[16], br[16];
#pragma unroll
  for (int k = 0; k < 16; ++k) {
    int e = base + k * 256 + t;
    br[k] = 0xFFFFFFFFu;
    if (e < ETOT) {
      int ty = e / N_EDGE, i = e - ty * N_EDGE;
      int d, s;
      if (ty == 0)      { d = duu[i]; s = suu[i]; }
      else if (ty == 1) { d = dub[i]; s = sub[i]; }
      else              { d = diu[i]; s = siu[i]; }
      int slot = ty * N_USER + d;
      int bu = slot >> BSH;
      int rank = atomicAdd(&h[bu], 1);
      pay[k] = (u32)s | ((u32)(slot & (SPAN - 1)) << 16);
      br[k]  = (u32)bu | ((u32)rank << 9);       // bu<=292 fits 9 bits; rank<4096
    }
  }
  __syncthreads();
  for (int i = t; i < NB; i += 256)
    h[i] = i * CAP + atomicAdd(&cursor[i], h[i]);   // block base within fixed bucket
  __syncthreads();
#pragma unroll
  for (int k = 0; k < 16; ++k) {
    if (br[k] != 0xFFFFFFFFu) {
      int bu = br[k] & 0x1FF, rank = (int)(br[k] >> 9);
      ebuf[h[bu] + rank] = pay[k];
    }
  }
}

// ---- csr v2: each block scans the 293 final cursor counts in-LDS for its compact
//      ebase, then builds off[]/ssrc[] from its fixed-capacity bucket region.
//      Blocks >=293: conversion part 2. ----
__global__ void __launch_bounds__(256) k_csr(const int* __restrict__ cursor, const u32* __restrict__ ebuf,
                                             int* __restrict__ off, u16* __restrict__ ssrc,
                                             const float* __restrict__ fu, const float* __restrict__ fi,
                                             u16* __restrict__ fb_u, u16* __restrict__ fb_i) {
  if (blockIdx.x >= NB) {                // conversion filler part 2
    conv_chunk((blockIdx.x - NB) * 2048 + 1601536, fu, fi, fb_u, fb_i);
    return;
  }
  __shared__ int sc[SPAN];
  __shared__ int so[SPAN];
  __shared__ int part[256];
  __shared__ int sebase;
  int t = threadIdx.x;
  int b = blockIdx.x;
  {  // bucket-count scan -> compact ebase for bucket b
    int a = (2 * t < NB) ? cursor[2 * t] : 0;
    int c = (2 * t + 1 < NB) ? cursor[2 * t + 1] : 0;
    part[t] = a + c; __syncthreads();
    for (int s = 1; s < 256; s <<= 1) {
      int y = (t >= s) ? part[t - s] : 0;
      __syncthreads(); part[t] += y; __syncthreads();
    }
    int ex = part[t] - (a + c);
    if (2 * t == b) sebase = ex;
    if (2 * t + 1 == b) sebase = ex + a;
    __syncthreads();
  }
  int ecnt = cursor[b];
  int ebase = sebase;
  int srcb = b * CAP;
  int sbase = b << BSH;
  int nslots = (NTOT - sbase < SPAN) ? (NTOT - sbase) : SPAN;
  for (int i = t; i < SPAN; i += 256) sc[i] = 0;
  __syncthreads();
  for (int j = t; j < ecnt; j += 256)
    atomicAdd(&sc[ebuf[srcb + j] >> 16], 1);
  __syncthreads();
  int s0 = sc[2 * t], s1 = sc[2 * t + 1];
  int tsum = s0 + s1;
  part[t] = tsum; __syncthreads();
  for (int s = 1; s < 256; s <<= 1) {
    int y = (t >= s) ? part[t - s] : 0;
    __syncthreads(); part[t] += y; __syncthreads();
  }
  int pbase = part[t] - tsum;
  so[2 * t]     = pbase;
  so[2 * t + 1] = pbase + s0;
  __syncthreads();
  for (int i = t; i < nslots; i += 256)
    off[sbase + i] = ebase + so[i];
  if (b == 0 && t == 0) off[NTOT] = ETOT;
  for (int i = t; i < SPAN; i += 256) sc[i] = so[i];   // cursors
  __syncthreads();
  for (int j = t; j < ecnt; j += 256) {
    u32 p = ebuf[srcb + j];
    int pos = atomicAdd(&sc[p >> 16], 1);
    ssrc[ebase + pos] = (u16)(p & 0xFFFFu);
  }
}

// ---- mean over user-table slots [0, 100000) ----
__global__ void __launch_bounds__(256) k_mean_u(const u16* __restrict__ fb_u,
                                                const int* __restrict__ off, const u16* __restrict__ ssrc,
                                                u16* __restrict__ ob) {
  int slot = blockIdx.x * 8 + (threadIdx.x >> 5);
  if (slot >= 100000) return;
  mean_slot(slot, threadIdx.x & 31, fb_u, off, ssrc, ob);
}

// ---- fused: [0,6250) mean over item-table slots [100000,150000);
//      [6250,6641) ITEM-pass GEMM (reads mean_ub from k_mean_u; writes item rows —
//      disjoint from concurrent mean_iu writes to user rows). 32KB LDS B-staging,
//      direct calibrated stores (m89 layout: col=lane&15, row=(lane>>4)*4+reg). ----
__global__ void __launch_bounds__(256) k_mi(const u16* __restrict__ fb_i,
                                            const int* __restrict__ off, const u16* __restrict__ ssrc,
                                            u16* __restrict__ ob, float* __restrict__ out,
                                            const u16* __restrict__ WT, const float* __restrict__ bub) {
  __shared__ u16 sB[16384];              // 32 KB: item B frags (KT=4 x 8nt x 64lane x 8u16)
  if (blockIdx.x < 6250) {
    int slot = 100000 + blockIdx.x * 8 + (threadIdx.x >> 5);
    if (slot < NTOT) mean_slot(slot, threadIdx.x & 31, fb_i, off, ssrc, ob);
    return;
  }
  int tid = threadIdx.x;
  int w = tid >> 6, lane = tid & 63, quad = lane >> 4, l16 = lane & 15;
  const u16* Wsrc = WT + 32768;          // WTi [n=128][k=128]
  for (int fid = tid; fid < 2048; fid += 256) {
    int fl = fid & 63, fnt = (fid >> 6) & 7, fkk = fid >> 9;
    int fq = fl >> 4, fl16 = fl & 15;
    const u16* src = Wsrc + (fnt * 16 + fl16) * 128 + fkk * 32 + fq * 8;
    *(uint4*)(sB + (size_t)fid * 8) = *(const uint4*)src;
  }
  int row0 = (blockIdx.x - 6250) * 128 + w * 32;
  int r0a = row0 + l16, r1a = row0 + 16 + l16;
  int rA0 = r0a < N_USER ? r0a : N_USER - 1;
  int rA1 = r1a < N_USER ? r1a : N_USER - 1;
  const u16* A0 = ob + 12800000 + (size_t)rA0 * 256 + quad * 8;
  const u16* A1 = ob + 12800000 + (size_t)rA1 * 256 + quad * 8;
  short8 af0[4], af1[4];
#pragma unroll
  for (int kk = 0; kk < 4; ++kk) {
    af0[kk] = *(const short8*)(A0 + kk * 32);
    af1[kk] = *(const short8*)(A1 + kk * 32);
  }
  int nA[2][4];
#pragma unroll
  for (int rt = 0; rt < 2; ++rt)
#pragma unroll
    for (int i = 0; i < 4; ++i) {
      int grow = row0 + rt * 16 + quad * 4 + i;
      nA[rt][i] = (grow < N_USER) ? (off[N_USER + grow + 1] - off[N_USER + grow]) : 0;
    }
  __syncthreads();
  floatx4 acc[2][8];
#pragma unroll
  for (int rt = 0; rt < 2; ++rt)
#pragma unroll
    for (int nt = 0; nt < 8; ++nt) acc[rt][nt] = (floatx4){0.f, 0.f, 0.f, 0.f};
#pragma unroll
  for (int kk = 0; kk < 4; ++kk) {
    const short8* bp = (const short8*)(sB + ((size_t)kk * 512 + lane) * 8);
#pragma unroll
    for (int nt = 0; nt < 8; ++nt) {
      short8 bf = bp[nt * 64];
      acc[0][nt] = __builtin_amdgcn_mfma_f32_16x16x32_bf16(af0[kk], bf, acc[0][nt], 0, 0, 0);
      acc[1][nt] = __builtin_amdgcn_mfma_f32_16x16x32_bf16(af1[kk], bf, acc[1][nt], 0, 0, 0);
    }
  }
#pragma unroll
  for (int rt = 0; rt < 2; ++rt) {
    int tbase = row0 + rt * 16;
#pragma unroll
    for (int nt = 0; nt < 8; ++nt) {
      int col = nt * 16 + l16;
      float bA = bub[col];
#pragma unroll
      for (int i = 0; i < 4; ++i) {
        int grow = tbase + quad * 4 + i;
        if (grow < N_USER) {
          float r = acc[rt][nt][i] + (nA[rt][i] > 0 ? bA : 0.f);
          out[((size_t)N_USER + grow) * D + col] = r;
        }
      }
    }
  }
}

// ---- final USER-pass GEMM (v5: 64KB LDS B frags, hoisted A/gate loads, coalesced
//      LDS-transposed epilogue). Launched with gridDim.y=1 -> users path only. ----
__global__ void __launch_bounds__(256, 2) k_out(float* out, const u16* __restrict__ WT,
                                                const float* __restrict__ buu, const float* __restrict__ bub,
                                                const float* __restrict__ biu, const int* __restrict__ off) {
  int users = (blockIdx.y == 0);
  int tid = threadIdx.x;
  int w = tid >> 6, lane = tid & 63, quad = lane >> 4, l16 = lane & 15;
  int KT = users ? 8 : 4;
  const u16* Wsrc = users ? WT : (WT + 32768);
  int wstride = users ? 256 : 128;

  __shared__ u16 sB[32768];              // 64 KB
  int nfrag = KT * 8 * 64;
  for (int fid = tid; fid < nfrag; fid += 256) {
    int fl = fid & 63, fnt = (fid >> 6) & 7, fkk = fid >> 9;
    int fq = fl >> 4, fl16 = fl & 15;
    const u16* src = Wsrc + (fnt * 16 + fl16) * wstride + fkk * 32 + fq * 8;
    *(uint4*)(sB + (size_t)fid * 8) = *(const uint4*)src;
  }

  int row0 = blockIdx.x * 128 + w * 32;
  const u16* ob = (const u16*)out;
  const u16* Abase = users ? ob : (ob + 12800000);
  size_t outoff = users ? 0 : (size_t)N_USER;

  int r0a = row0 + l16, r1a = row0 + 16 + l16;
  int rA0 = r0a < N_USER ? r0a : N_USER - 1;
  int rA1 = r1a < N_USER ? r1a : N_USER - 1;
  const u16* A0 = Abase + (size_t)rA0 * 256 + quad * 8;
  const u16* A1 = Abase + (size_t)rA1 * 256 + quad * 8;

  short8 af0[8], af1[8];
#pragma unroll
  for (int kk = 0; kk < 8; ++kk) {
    if (kk < KT) {
      af0[kk] = *(const short8*)(A0 + kk * 32);
      af1[kk] = *(const short8*)(A1 + kk * 32);
    }
  }
  int nA[2][4], nB[2][4];
#pragma unroll
  for (int rt = 0; rt < 2; ++rt)
#pragma unroll
    for (int i = 0; i < 4; ++i) {
      int grow = row0 + rt * 16 + quad * 4 + i;
      bool ok = grow < N_USER;
      if (users) {
        nA[rt][i] = ok ? (off[grow + 1] - off[grow]) : 0;
        nB[rt][i] = ok ? (off[2 * N_USER + grow + 1] - off[2 * N_USER + grow]) : 0;
      } else {
        nA[rt][i] = ok ? (off[N_USER + grow + 1] - off[N_USER + grow]) : 0;
        nB[rt][i] = 0;
      }
    }
  __syncthreads();

  floatx4 acc[2][8];
#pragma unroll
  for (int rt = 0; rt < 2; ++rt)
#pragma unroll
    for (int nt = 0; nt < 8; ++nt) acc[rt][nt] = (floatx4){0.f, 0.f, 0.f, 0.f};

#pragma unroll
  for (int kk = 0; kk < 8; ++kk) {
    if (kk < KT) {
      const short8* bp = (const short8*)(sB + ((size_t)kk * 512 + lane) * 8);
#pragma unroll
      for (int nt = 0; nt < 8; ++nt) {
        short8 bf = bp[nt * 64];
        acc[0][nt] = __builtin_amdgcn_mfma_f32_16x16x32_bf16(af0[kk], bf, acc[0][nt], 0, 0, 0);
        acc[1][nt] = __builtin_amdgcn_mfma_f32_16x16x32_bf16(af1[kk], bf, acc[1][nt], 0, 0, 0);
      }
    }
  }

  float* sO = (float*)sB;
#pragma unroll
  for (int rt = 0; rt < 2; ++rt) {
    __syncthreads();
#pragma unroll
    for (int nt = 0; nt < 8; ++nt) {
      int col = nt * 16 + l16;
      float bA = users ? buu[col] : bub[col];
      float bB = users ? biu[col] : 0.f;
#pragma unroll
      for (int i = 0; i < 4; ++i) {
        float r = acc[rt][nt][i] + (nA[rt][i] > 0 ? bA : 0.f) + (nB[rt][i] > 0 ? bB : 0.f);
        sO[(w * 16 + quad * 4 + i) * 132 + col] = r;
      }
    }
    __syncthreads();
#pragma unroll
    for (int it = 0; it < 8; ++it) {
      int idx = it * 256 + tid;
      int lr = idx >> 5, cg = (idx & 31) * 4;
      int grow = blockIdx.x * 128 + (lr >> 4) * 32 + rt * 16 + (lr & 15);
      if (grow < N_USER) {
        float4 v = make_float4(sO[lr * 132 + cg], sO[lr * 132 + cg + 1],
                               sO[lr * 132 + cg + 2], sO[lr * 132 + cg + 3]);
        *(float4*)(out + (outoff + (size_t)grow) * D + cg) = v;
      }
    }
  }
}

extern "C" void kernel_launch(void* const* d_in, const int* in_sizes, int n_in,
                              void* d_out, int out_size, void* d_ws, size_t ws_size,
                              hipStream_t stream) {
  const float* fu  = (const float*)d_in[0];
  const float* fi  = (const float*)d_in[1];
  const float* Wuu = (const float*)d_in[2];
  const float* buu = (const float*)d_in[3];
  const float* Wub = (const float*)d_in[4];
  const float* bub = (const float*)d_in[5];
  const float* Wiu = (const float*)d_in[6];
  const float* biu = (const float*)d_in[7];
  const int* suu = (const int*)d_in[8];
  const int* duu = (const int*)d_in[9];
  const int* sub = (const int*)d_in[10];
  const int* dub = (const int*)d_in[11];
  const int* siu = (const int*)d_in[12];
  const int* diu = (const int*)d_in[13];
  float* out = (float*)d_out;   // f32: [out_user 50000x128 | out_item 50000x128]
  u16* ob = (u16*)d_out;
  // d_out scratch: user row r [0,256B)=mean_uu [256,512B)=mean_iu; item row r [0,256B)=mean_ub

  // workspace layout (38.3 MB), offsets in INTs:
  int* wsi    = (int*)d_ws;
  int* off    = wsi;                        // [150001] pad 150016
  int* cursor = wsi + 150016;               // [293] pad 320
  u32* ebuf   = (u32*)(wsi + 150336);       // [293*7168 = 2,100,224] (8.4 MB)
  u16* ssrc   = (u16*)(wsi + 2250560);      // [1800000] u16 (3.6 MB)
  u16* WT     = (u16*)(wsi + 3150560);      // WTu 32768 + WTi 16384 u16 (96 KB)
  u16* fb_u   = (u16*)(wsi + 3175136);      // 50000x128 bf16 (12.8 MB)
  u16* fb_i   = (u16*)(wsi + 6375136);      // 50000x128 bf16 (12.8 MB)

  hipMemsetAsync(cursor, 0, 320 * sizeof(int), stream);
  // place (440) + WT (3) + conversion part 1 (782)
  k_bplace<<<1225, 256, 0, stream>>>(suu, duu, sub, dub, siu, diu, cursor, ebuf,
                                     Wuu, Wub, Wiu, WT, fu, fi, fb_u, fb_i);
  // csr (293) + conversion part 2 (781)
  k_csr<<<NB + 781, 256, 0, stream>>>(cursor, ebuf, off, ssrc, fu, fi, fb_u, fb_i);
  k_mean_u<<<12500, 256, 0, stream>>>(fb_u, off, ssrc, ob);
  // mean_i (6250) + hidden item-pass GEMM (391)
  k_mi<<<6641, 256, 0, stream>>>(fb_i, off, ssrc, ob, out, WT, bub);
  // user pass only
  k_out<<<391, 256, 0, stream>>>(out, WT, buu, bub, biu, off);
}

// Round 15
// 258.018 us; speedup vs baseline: 1.0488x; 1.0488x over previous
//
#include <hip/hip_runtime.h>
#include <stdint.h>
#include <string.h>

#define N_USER 50000
#define N_ITEM 50000
#define N_EDGE 600000
#define D 128
#define NTOT 150000      // 3 * 50000 destination slots (uu | ub | iu)
#define ETOT 1800000
#define NB 293           // buckets = ceil(NTOT / SPAN)
#define BSH 9
#define SPAN 512         // slots per bucket
#define CHUNK 4096       // edges per block in bucket kernels (16/thread)
#define CAP 7168         // fixed bucket capacity (expected max ~6450, 13-sigma margin)

typedef unsigned short u16;
typedef unsigned int   u32;
typedef __attribute__((ext_vector_type(8))) short short8;   // 8 bf16 (MFMA A/B frag)
typedef __attribute__((ext_vector_type(4))) float floatx4;  // MFMA C/D frag

static __device__ __forceinline__ u16 f2b(float f) {        // f32 -> bf16 RNE
  u32 x; memcpy(&x, &f, 4);
  u32 r = x + 0x7fffu + ((x >> 16) & 1u);
  return (u16)(r >> 16);
}
static __device__ __forceinline__ float blo2f(u32 v) {
  u32 x = v << 16; float f; memcpy(&f, &x, 4); return f;
}
static __device__ __forceinline__ float bhi2f(u32 v) {
  u32 x = v & 0xffff0000u; float f; memcpy(&f, &x, 4); return f;
}

// streaming f32->bf16 conversion: 8 float4-groups per thread from group cbase.
// Total 3.2M groups (fu then fi). Rides as filler blocks on under-utilized launches.
static __device__ __forceinline__ void conv_chunk(int cbase,
    const float* __restrict__ fu, const float* __restrict__ fi,
    u16* __restrict__ fb_u, u16* __restrict__ fb_i) {
#pragma unroll
  for (int u = 0; u < 8; ++u) {
    int gid = cbase + u * 256 + (int)threadIdx.x;
    if (gid < 3200000) {
      const float* src = fu; u16* dst = fb_u; int g = gid;
      if (g >= 1600000) { g -= 1600000; src = fi; dst = fb_i; }
      float4 v = ((const float4*)src)[g];
      union { u16 q[4]; uint2 d; } pk;
      pk.q[0] = f2b(v.x); pk.q[1] = f2b(v.y); pk.q[2] = f2b(v.z); pk.q[3] = f2b(v.w);
      ((uint2*)dst)[g] = pk.d;
    }
  }
}

// gather-mean body (proven v5): half-wave per slot, uint2/lane, shfl-broadcast
// edge srcs, 8/4/1 load batches. Writes bf16 mean into d_out per layout.
static __device__ __forceinline__ void mean_slot(int slot, int lane,
    const u16* __restrict__ fb, const int* __restrict__ off,
    const u16* __restrict__ ssrc, u16* __restrict__ ob) {
  int t = slot / N_USER;
  int d = slot - t * N_USER;
  int s = off[slot], e = off[slot + 1];
  int n = e - s;
  int my_src = (lane < n) ? (int)ssrc[s + lane] : 0;
  float a0 = 0.f, a1 = 0.f, a2 = 0.f, a3 = 0.f;
  int m = (n < 32) ? n : 32;
  int i = 0;
  for (; i + 8 <= m; i += 8) {
    int sA[8];
#pragma unroll
    for (int k = 0; k < 8; ++k) sA[k] = __shfl(my_src, i + k, 32);
    uint2 v[8];
#pragma unroll
    for (int k = 0; k < 8; ++k) v[k] = ((const uint2*)(fb + (size_t)sA[k] * D))[lane];
#pragma unroll
    for (int k = 0; k < 8; ++k) {
      a0 += blo2f(v[k].x); a1 += bhi2f(v[k].x);
      a2 += blo2f(v[k].y); a3 += bhi2f(v[k].y);
    }
  }
  for (; i + 4 <= m; i += 4) {
    int s0 = __shfl(my_src, i, 32);
    int s1 = __shfl(my_src, i + 1, 32);
    int s2 = __shfl(my_src, i + 2, 32);
    int s3 = __shfl(my_src, i + 3, 32);
    uint2 v0 = ((const uint2*)(fb + (size_t)s0 * D))[lane];
    uint2 v1 = ((const uint2*)(fb + (size_t)s1 * D))[lane];
    uint2 v2 = ((const uint2*)(fb + (size_t)s2 * D))[lane];
    uint2 v3 = ((const uint2*)(fb + (size_t)s3 * D))[lane];
    a0 += blo2f(v0.x) + blo2f(v1.x) + blo2f(v2.x) + blo2f(v3.x);
    a1 += bhi2f(v0.x) + bhi2f(v1.x) + bhi2f(v2.x) + bhi2f(v3.x);
    a2 += blo2f(v0.y) + blo2f(v1.y) + blo2f(v2.y) + blo2f(v3.y);
    a3 += bhi2f(v0.y) + bhi2f(v1.y) + bhi2f(v2.y) + bhi2f(v3.y);
  }
  for (; i < m; ++i) {
    int sr = __shfl(my_src, i, 32);
    uint2 v = ((const uint2*)(fb + (size_t)sr * D))[lane];
    a0 += blo2f(v.x); a1 += bhi2f(v.x);
    a2 += blo2f(v.y); a3 += bhi2f(v.y);
  }
  for (int j = s + 32; j < e; ++j) {
    int sr = ssrc[j];
    uint2 v = ((const uint2*)(fb + (size_t)sr * D))[lane];
    a0 += blo2f(v.x); a1 += bhi2f(v.x);
    a2 += blo2f(v.y); a3 += bhi2f(v.y);
  }
  float inv = (n > 0) ? 1.0f / (float)n : 0.f;
  u32 p0 = (u32)f2b(a0 * inv) | ((u32)f2b(a1 * inv) << 16);
  u32 p1 = (u32)f2b(a2 * inv) | ((u32)f2b(a3 * inv) << 16);
  u32* mrow;
  if (t == 0)      mrow = (u32*)(ob + (size_t)d * 256);              // mean_uu
  else if (t == 2) mrow = (u32*)(ob + (size_t)d * 256 + 128);        // mean_iu
  else             mrow = (u32*)(ob + 12800000 + (size_t)d * 256);   // mean_ub
  ((uint2*)mrow)[lane] = make_uint2(p0, p1);
}

// ---- bplace v2: fixed-capacity buckets, NO histogram pre-pass. [0,440) place;
//      [440,443) weight transpose; [443,1225) conversion part 1 ----
__global__ void __launch_bounds__(256) k_bplace(
    const int* __restrict__ suu, const int* __restrict__ duu,
    const int* __restrict__ sub, const int* __restrict__ dub,
    const int* __restrict__ siu, const int* __restrict__ diu,
    int* __restrict__ cursor, u32* __restrict__ ebuf,
    const float* __restrict__ W0, const float* __restrict__ W1,
    const float* __restrict__ W2, u16* __restrict__ WT,
    const float* __restrict__ fu, const float* __restrict__ fi,
    u16* __restrict__ fb_u, u16* __restrict__ fb_i) {
  int bid = blockIdx.x;
  if (bid >= 443) {                      // conversion filler part 1
    conv_chunk((bid - 443) * 2048, fu, fi, fb_u, fb_i);
    return;
  }
  if (bid >= 440) {                      // weight transpose + bf16 (stacked)
    int wsel = bid - 440;
    for (int idx = threadIdx.x; idx < D * D; idx += 256) {
      int n = idx >> 7, k = idx & 127;
      if (wsel == 0)      WT[n * 256 + k]       = f2b(W0[k * D + n]);
      else if (wsel == 1) WT[n * 256 + 128 + k] = f2b(W2[k * D + n]);
      else                WT[32768 + n * D + k] = f2b(W1[k * D + n]);
    }
    return;
  }
  __shared__ int h[NB];
  int t = threadIdx.x;
  for (int i = t; i < NB; i += 256) h[i] = 0;
  __syncthreads();
  int base = bid * CHUNK;
  u32 pay[16], br[16];
#pragma unroll
  for (int k = 0; k < 16; ++k) {
    int e = base + k * 256 + t;
    br[k] = 0xFFFFFFFFu;
    if (e < ETOT) {
      int ty = e / N_EDGE, i = e - ty * N_EDGE;
      int d, s;
      if (ty == 0)      { d = duu[i]; s = suu[i]; }
      else if (ty == 1) { d = dub[i]; s = sub[i]; }
      else              { d = diu[i]; s = siu[i]; }
      int slot = ty * N_USER + d;
      int bu = slot >> BSH;
      int rank = atomicAdd(&h[bu], 1);
      pay[k] = (u32)s | ((u32)(slot & (SPAN - 1)) << 16);
      br[k]  = (u32)bu | ((u32)rank << 9);       // bu<=292 fits 9 bits; rank<4096
    }
  }
  __syncthreads();
  for (int i = t; i < NB; i += 256)
    h[i] = i * CAP + atomicAdd(&cursor[i], h[i]);   // block base within fixed bucket
  __syncthreads();
#pragma unroll
  for (int k = 0; k < 16; ++k) {
    if (br[k] != 0xFFFFFFFFu) {
      int bu = br[k] & 0x1FF, rank = (int)(br[k] >> 9);
      ebuf[h[bu] + rank] = pay[k];
    }
  }
}

// ---- csr v2: each block scans the 293 final cursor counts in-LDS for its compact
//      ebase, then builds off[]/ssrc[] from its fixed-capacity bucket region.
//      Blocks >=293: conversion part 2. ----
__global__ void __launch_bounds__(256) k_csr(const int* __restrict__ cursor, const u32* __restrict__ ebuf,
                                             int* __restrict__ off, u16* __restrict__ ssrc,
                                             const float* __restrict__ fu, const float* __restrict__ fi,
                                             u16* __restrict__ fb_u, u16* __restrict__ fb_i) {
  if (blockIdx.x >= NB) {                // conversion filler part 2
    conv_chunk((blockIdx.x - NB) * 2048 + 1601536, fu, fi, fb_u, fb_i);
    return;
  }
  __shared__ int sc[SPAN];
  __shared__ int so[SPAN];
  __shared__ int part[256];
  __shared__ int sebase;
  int t = threadIdx.x;
  int b = blockIdx.x;
  {  // bucket-count scan -> compact ebase for bucket b
    int a = (2 * t < NB) ? cursor[2 * t] : 0;
    int c = (2 * t + 1 < NB) ? cursor[2 * t + 1] : 0;
    part[t] = a + c; __syncthreads();
    for (int s = 1; s < 256; s <<= 1) {
      int y = (t >= s) ? part[t - s] : 0;
      __syncthreads(); part[t] += y; __syncthreads();
    }
    int ex = part[t] - (a + c);
    if (2 * t == b) sebase = ex;
    if (2 * t + 1 == b) sebase = ex + a;
    __syncthreads();
  }
  int ecnt = cursor[b];
  int ebase = sebase;
  int srcb = b * CAP;
  int sbase = b << BSH;
  int nslots = (NTOT - sbase < SPAN) ? (NTOT - sbase) : SPAN;
  for (int i = t; i < SPAN; i += 256) sc[i] = 0;
  __syncthreads();
  for (int j = t; j < ecnt; j += 256)
    atomicAdd(&sc[ebuf[srcb + j] >> 16], 1);
  __syncthreads();
  int s0 = sc[2 * t], s1 = sc[2 * t + 1];
  int tsum = s0 + s1;
  part[t] = tsum; __syncthreads();
  for (int s = 1; s < 256; s <<= 1) {
    int y = (t >= s) ? part[t - s] : 0;
    __syncthreads(); part[t] += y; __syncthreads();
  }
  int pbase = part[t] - tsum;
  so[2 * t]     = pbase;
  so[2 * t + 1] = pbase + s0;
  __syncthreads();
  for (int i = t; i < nslots; i += 256)
    off[sbase + i] = ebase + so[i];
  if (b == 0 && t == 0) off[NTOT] = ETOT;
  for (int i = t; i < SPAN; i += 256) sc[i] = so[i];   // cursors
  __syncthreads();
  for (int j = t; j < ecnt; j += 256) {
    u32 p = ebuf[srcb + j];
    int pos = atomicAdd(&sc[p >> 16], 1);
    ssrc[ebase + pos] = (u16)(p & 0xFFFFu);
  }
}

// ---- mean over user-table slots [0, 100000) ----
__global__ void __launch_bounds__(256) k_mean_u(const u16* __restrict__ fb_u,
                                                const int* __restrict__ off, const u16* __restrict__ ssrc,
                                                u16* __restrict__ ob) {
  int slot = blockIdx.x * 8 + (threadIdx.x >> 5);
  if (slot >= 100000) return;
  mean_slot(slot, threadIdx.x & 31, fb_u, off, ssrc, ob);
}

// ---- mean over item-table slots [100000, 150000) — NO LDS (occupancy-sensitive;
//      r14 lesson: fusing with 32KB-LDS GEMM throttled this from 19 to ~50 us) ----
__global__ void __launch_bounds__(256) k_mean_i(const u16* __restrict__ fb_i,
                                                const int* __restrict__ off, const u16* __restrict__ ssrc,
                                                u16* __restrict__ ob) {
  int slot = 100000 + blockIdx.x * 8 + (threadIdx.x >> 5);
  if (slot >= NTOT) return;
  mean_slot(slot, threadIdx.x & 31, fb_i, off, ssrc, ob);
}

// ---- final GEMM (v5: 64KB LDS B frags, hoisted A/gate loads, coalesced
//      LDS-transposed epilogue). dim3(391,2): y=0 user pass, y=1 item pass. ----
__global__ void __launch_bounds__(256, 2) k_out(float* out, const u16* __restrict__ WT,
                                                const float* __restrict__ buu, const float* __restrict__ bub,
                                                const float* __restrict__ biu, const int* __restrict__ off) {
  int users = (blockIdx.y == 0);
  int tid = threadIdx.x;
  int w = tid >> 6, lane = tid & 63, quad = lane >> 4, l16 = lane & 15;
  int KT = users ? 8 : 4;
  const u16* Wsrc = users ? WT : (WT + 32768);
  int wstride = users ? 256 : 128;

  __shared__ u16 sB[32768];              // 64 KB
  int nfrag = KT * 8 * 64;
  for (int fid = tid; fid < nfrag; fid += 256) {
    int fl = fid & 63, fnt = (fid >> 6) & 7, fkk = fid >> 9;
    int fq = fl >> 4, fl16 = fl & 15;
    const u16* src = Wsrc + (fnt * 16 + fl16) * wstride + fkk * 32 + fq * 8;
    *(uint4*)(sB + (size_t)fid * 8) = *(const uint4*)src;
  }

  int row0 = blockIdx.x * 128 + w * 32;
  const u16* ob = (const u16*)out;
  const u16* Abase = users ? ob : (ob + 12800000);
  size_t outoff = users ? 0 : (size_t)N_USER;

  int r0a = row0 + l16, r1a = row0 + 16 + l16;
  int rA0 = r0a < N_USER ? r0a : N_USER - 1;
  int rA1 = r1a < N_USER ? r1a : N_USER - 1;
  const u16* A0 = Abase + (size_t)rA0 * 256 + quad * 8;
  const u16* A1 = Abase + (size_t)rA1 * 256 + quad * 8;

  short8 af0[8], af1[8];
#pragma unroll
  for (int kk = 0; kk < 8; ++kk) {
    if (kk < KT) {
      af0[kk] = *(const short8*)(A0 + kk * 32);
      af1[kk] = *(const short8*)(A1 + kk * 32);
    }
  }
  int nA[2][4], nB[2][4];
#pragma unroll
  for (int rt = 0; rt < 2; ++rt)
#pragma unroll
    for (int i = 0; i < 4; ++i) {
      int grow = row0 + rt * 16 + quad * 4 + i;
      bool ok = grow < N_USER;
      if (users) {
        nA[rt][i] = ok ? (off[grow + 1] - off[grow]) : 0;
        nB[rt][i] = ok ? (off[2 * N_USER + grow + 1] - off[2 * N_USER + grow]) : 0;
      } else {
        nA[rt][i] = ok ? (off[N_USER + grow + 1] - off[N_USER + grow]) : 0;
        nB[rt][i] = 0;
      }
    }
  __syncthreads();

  floatx4 acc[2][8];
#pragma unroll
  for (int rt = 0; rt < 2; ++rt)
#pragma unroll
    for (int nt = 0; nt < 8; ++nt) acc[rt][nt] = (floatx4){0.f, 0.f, 0.f, 0.f};

#pragma unroll
  for (int kk = 0; kk < 8; ++kk) {
    if (kk < KT) {
      const short8* bp = (const short8*)(sB + ((size_t)kk * 512 + lane) * 8);
#pragma unroll
      for (int nt = 0; nt < 8; ++nt) {
        short8 bf = bp[nt * 64];
        acc[0][nt] = __builtin_amdgcn_mfma_f32_16x16x32_bf16(af0[kk], bf, acc[0][nt], 0, 0, 0);
        acc[1][nt] = __builtin_amdgcn_mfma_f32_16x16x32_bf16(af1[kk], bf, acc[1][nt], 0, 0, 0);
      }
    }
  }

  float* sO = (float*)sB;
#pragma unroll
  for (int rt = 0; rt < 2; ++rt) {
    __syncthreads();
#pragma unroll
    for (int nt = 0; nt < 8; ++nt) {
      int col = nt * 16 + l16;
      float bA = users ? buu[col] : bub[col];
      float bB = users ? biu[col] : 0.f;
#pragma unroll
      for (int i = 0; i < 4; ++i) {
        float r = acc[rt][nt][i] + (nA[rt][i] > 0 ? bA : 0.f) + (nB[rt][i] > 0 ? bB : 0.f);
        sO[(w * 16 + quad * 4 + i) * 132 + col] = r;
      }
    }
    __syncthreads();
#pragma unroll
    for (int it = 0; it < 8; ++it) {
      int idx = it * 256 + tid;
      int lr = idx >> 5, cg = (idx & 31) * 4;
      int grow = blockIdx.x * 128 + (lr >> 4) * 32 + rt * 16 + (lr & 15);
      if (grow < N_USER) {
        float4 v = make_float4(sO[lr * 132 + cg], sO[lr * 132 + cg + 1],
                               sO[lr * 132 + cg + 2], sO[lr * 132 + cg + 3]);
        *(float4*)(out + (outoff + (size_t)grow) * D + cg) = v;
      }
    }
  }
}

extern "C" void kernel_launch(void* const* d_in, const int* in_sizes, int n_in,
                              void* d_out, int out_size, void* d_ws, size_t ws_size,
                              hipStream_t stream) {
  const float* fu  = (const float*)d_in[0];
  const float* fi  = (const float*)d_in[1];
  const float* Wuu = (const float*)d_in[2];
  const float* buu = (const float*)d_in[3];
  const float* Wub = (const float*)d_in[4];
  const float* bub = (const float*)d_in[5];
  const float* Wiu = (const float*)d_in[6];
  const float* biu = (const float*)d_in[7];
  const int* suu = (const int*)d_in[8];
  const int* duu = (const int*)d_in[9];
  const int* sub = (const int*)d_in[10];
  const int* dub = (const int*)d_in[11];
  const int* siu = (const int*)d_in[12];
  const int* diu = (const int*)d_in[13];
  float* out = (float*)d_out;   // f32: [out_user 50000x128 | out_item 50000x128]
  u16* ob = (u16*)d_out;
  // d_out scratch: user row r [0,256B)=mean_uu [256,512B)=mean_iu; item row r [0,256B)=mean_ub

  // workspace layout (38.3 MB), offsets in INTs:
  int* wsi    = (int*)d_ws;
  int* off    = wsi;                        // [150001] pad 150016
  int* cursor = wsi + 150016;               // [293] pad 320
  u32* ebuf   = (u32*)(wsi + 150336);       // [293*7168 = 2,100,224] (8.4 MB)
  u16* ssrc   = (u16*)(wsi + 2250560);      // [1800000] u16 (3.6 MB)
  u16* WT     = (u16*)(wsi + 3150560);      // WTu 32768 + WTi 16384 u16 (96 KB)
  u16* fb_u   = (u16*)(wsi + 3175136);      // 50000x128 bf16 (12.8 MB)
  u16* fb_i   = (u16*)(wsi + 6375136);      // 50000x128 bf16 (12.8 MB)

  hipMemsetAsync(cursor, 0, 320 * sizeof(int), stream);
  // place (440) + WT (3) + conversion part 1 (782)
  k_bplace<<<1225, 256, 0, stream>>>(suu, duu, sub, dub, siu, diu, cursor, ebuf,
                                     Wuu, Wub, Wiu, WT, fu, fi, fb_u, fb_i);
  // csr (293) + conversion part 2 (781)
  k_csr<<<NB + 781, 256, 0, stream>>>(cursor, ebuf, off, ssrc, fu, fi, fb_u, fb_i);
  k_mean_u<<<12500, 256, 0, stream>>>(fb_u, off, ssrc, ob);
  k_mean_i<<<6250, 256, 0, stream>>>(fb_i, off, ssrc, ob);
  k_out<<<dim3(391, 2), 256, 0, stream>>>(out, WT, buu, bub, biu, off);
}